// Round 6
// baseline (132.992 us; speedup 1.0000x reference)
//
#include <hip/hip_runtime.h>
#include <cmath>

#define NN 64
#define CC 96
#define TT 128
#define VV 25
#define SS 3
#define TB 4
#define NTB (TT/TB)          /* 32 */
#define ROWS (TB*VV)         /* 100 */
#define XTROWS 112

#define XTP 104              /* xT row pad (bf16 elems), 208B rows */
#define XFP 104              /* xf [c][i] staging pitch */
#define QKP 200              /* qk row pad, 400B rows */
#define VP  132              /* val row pitch: 128 i' cols + 4 */
#define YP  104              /* yL row pitch */

typedef __attribute__((ext_vector_type(8))) __bf16 bf16x8;
typedef __attribute__((ext_vector_type(4))) float f32x4;

#define MFMA16(a,b,c) __builtin_amdgcn_mfma_f32_16x16x32_bf16((a),(b),(c),0,0,0)

__constant__ int JP[25] = {0,0,1,1,2,2,2,3,4,4,4,5,6,6,7,7,8,8,9,9,0,3,3,5,5};
__constant__ int JB[25] = {4,4,4,4,0,0,0,0,1,1,1,1,2,2,2,2,3,3,3,3,4,0,0,1,1};

__device__ inline unsigned short f2b(float f) {
  unsigned int u = __float_as_uint(f);
  u += 0x7fffu + ((u >> 16) & 1u);
  return (unsigned short)(u >> 16);
}
__device__ inline bf16x8 ldbf8(const unsigned short* p) {
  union { uint4 u; bf16x8 b; } z;
  z.u = *(const uint4*)p;
  return z.b;
}
__device__ inline f32x4 fz() {
  f32x4 z; z[0] = 0.f; z[1] = 0.f; z[2] = 0.f; z[3] = 0.f; return z;
}

// ---------------------------------------------------------------------------
// k0: weights -> bf16 in ws; BN scale/shift precompute
// ---------------------------------------------------------------------------
__global__ __launch_bounds__(256) void k0(
    const float* __restrict__ w_in, const float* __restrict__ w_ff,
    const float* __restrict__ b_ff, const float* __restrict__ gam,
    const float* __restrict__ bet, const float* __restrict__ mea,
    const float* __restrict__ var,
    unsigned short* __restrict__ wbin, unsigned short* __restrict__ wbff,
    float* __restrict__ scsh)
{
  int i = blockIdx.x * 256 + threadIdx.x;
  if (i < 288 * 96) wbin[i] = f2b(w_in[i]);
  if (i < 96 * 96)  wbff[i] = f2b(w_ff[i]);
  if (i < 96) {
    float sc = gam[i] * rsqrtf(var[i] + 1e-5f);
    scsh[i]      = sc;
    scsh[96 + i] = (b_ff[i] - mea[i]) * sc + bet[i];
  }
}

// ---------------------------------------------------------------------------
// Staging helpers (k1): coalesced f32->bf16 into xf[c][i], then LDS transpose
// to xT[i][c]; the transpose pass ALSO stores xw[n][t][32][96] to ws so k3
// needs no x staging.  (v-pad rows 25..31 of xw stay uninitialized; their
// garbage is masked at val-write time in k3.)
// ---------------------------------------------------------------------------
__device__ inline void stageA(const float* __restrict__ xb,
                              unsigned short* __restrict__ xf, int tid)
{
  for (int e = tid; e < CC * (ROWS / 4); e += 256) {
    int i4 = e % (ROWS / 4), c = e / (ROWS / 4);
    float4 v = *(const float4*)&xb[(size_t)c * (TT * VV) + i4 * 4];
    ushort4 h;
    h.x = f2b(v.x); h.y = f2b(v.y); h.z = f2b(v.z); h.w = f2b(v.w);
    *(ushort4*)&xf[c * XFP + i4 * 4] = h;
  }
}
__device__ inline void stageB(const unsigned short* __restrict__ xf,
                              unsigned short* __restrict__ xT,
                              unsigned short* __restrict__ xwp, int tid)
{
  for (int e = tid; e < ROWS * (CC / 4); e += 256) {
    int i = e % ROWS, c4 = e / ROWS;
    ushort4 h;
    h.x = xf[(c4 * 4 + 0) * XFP + i];
    h.y = xf[(c4 * 4 + 1) * XFP + i];
    h.z = xf[(c4 * 4 + 2) * XFP + i];
    h.w = xf[(c4 * 4 + 3) * XFP + i];
    *(ushort4*)&xT[i * XTP + c4 * 4] = h;
    int dt = i / VV, v = i - dt * VV;
    *(ushort4*)&xwp[(size_t)(dt * 32 + v) * 96 + c4 * 4] = h;
  }
}

// ---------------------------------------------------------------------------
// k1: per (n, tb): QK GEMM (MFMA) -> Gram partials; also emits xw tile
// ---------------------------------------------------------------------------
__global__ __launch_bounds__(256, 2) void k1(
    const float* __restrict__ x, const unsigned short* __restrict__ wbin,
    const float* __restrict__ b_in, float* __restrict__ partG,
    unsigned short* __restrict__ xw)
{
  __shared__ __align__(16) unsigned short xT[XTROWS * XTP];   // 23296 B
  __shared__ __align__(16) unsigned short qk[XTROWS * QKP];   // 44800 B; xf alias
  __shared__ float bL[192];
  unsigned short* xf = qk;

  const int tid  = threadIdx.x;
  const int wid  = tid >> 6, lane = tid & 63;
  const int lrow = lane & 15;
  const int lk8  = (lane >> 4) << 3;
  const int ldr4 = (lane >> 4) << 2;
  const int tb = blockIdx.x & (NTB - 1);
  const int n  = blockIdx.x >> 5;
  const int t0 = tb * TB;

  const float* xb = x + (size_t)n * CC * TT * VV + (size_t)t0 * VV;
  unsigned short* xwp = xw + (size_t)(n * TT + t0) * 32 * 96;

  stageA(xb, xf, tid);
  if (tid < 192) bL[tid] = b_in[tid];
  __syncthreads();
  stageB(xf, xT, xwp, tid);
  __syncthreads();

  // QK GEMM: D[o=0..191][col=0..111] ; wave handles mf = 3*wid..3*wid+2
  f32x4 acc[3][7];
  #pragma unroll
  for (int i = 0; i < 3; ++i)
    #pragma unroll
    for (int nf = 0; nf < 7; ++nf) acc[i][nf] = fz();

  #pragma unroll
  for (int ks = 0; ks < 3; ++ks) {
    bf16x8 a[3];
    #pragma unroll
    for (int i = 0; i < 3; ++i)
      a[i] = ldbf8(&wbin[((wid * 3 + i) * 16 + lrow) * 96 + ks * 32 + lk8]);
    #pragma unroll
    for (int nf = 0; nf < 7; ++nf) {
      bf16x8 b = ldbf8(&xT[(nf * 16 + lrow) * XTP + ks * 32 + lk8]);
      #pragma unroll
      for (int i = 0; i < 3; ++i)
        acc[i][nf] = MFMA16(a[i], b, acc[i][nf]);
    }
  }
  // bias + bf16 + store to qk[col][o]
  #pragma unroll
  for (int i = 0; i < 3; ++i) {
    int ob = (wid * 3 + i) * 16 + ldr4;
    float4 bb = *(const float4*)&bL[ob];
    #pragma unroll
    for (int nf = 0; nf < 7; ++nf) {
      int col = nf * 16 + lrow;
      ushort4 h;
      h.x = f2b(acc[i][nf][0] + bb.x);
      h.y = f2b(acc[i][nf][1] + bb.y);
      h.z = f2b(acc[i][nf][2] + bb.z);
      h.w = f2b(acc[i][nf][3] + bb.w);
      *(ushort4*)&qk[col * QKP + ob] = h;
    }
  }
  __syncthreads();

  // Gram: waves 0..2, s = wid
  if (wid < 3) {
    const int s = wid;
    f32x4 g[2][2];
    g[0][0] = fz(); g[0][1] = fz(); g[1][0] = fz(); g[1][1] = fz();
    #pragma unroll
    for (int dt = 0; dt < TB; ++dt) {
      int r0 = dt * VV;
      bf16x8 a0 = ldbf8(&qk[(r0 + lrow) * QKP + s * 32 + lk8]);
      bf16x8 a1 = ldbf8(&qk[(r0 + 16 + lrow) * QKP + s * 32 + lk8]);
      bf16x8 b0 = ldbf8(&qk[(r0 + lrow) * QKP + 96 + s * 32 + lk8]);
      bf16x8 b1 = ldbf8(&qk[(r0 + 16 + lrow) * QKP + 96 + s * 32 + lk8]);
      g[0][0] = MFMA16(a0, b0, g[0][0]);
      g[0][1] = MFMA16(a0, b1, g[0][1]);
      g[1][0] = MFMA16(a1, b0, g[1][0]);
      g[1][1] = MFMA16(a1, b1, g[1][1]);
    }
    float* pg = partG + ((size_t)tb * (NN * SS) + (n * SS + s)) * (VV * VV);
    #pragma unroll
    for (int mi = 0; mi < 2; ++mi)
      #pragma unroll
      for (int ni = 0; ni < 2; ++ni)
        #pragma unroll
        for (int r = 0; r < 4; ++r) {
          int u = mi * 16 + ldr4 + r, v = ni * 16 + lrow;
          if (u < VV && v < VV) pg[u * VV + v] = g[mi][ni][r];
        }
  }
}

// ---------------------------------------------------------------------------
// k2: reduce partials, tanh + positional gathers -> att bf16 [ns][32][32]
// ---------------------------------------------------------------------------
__global__ __launch_bounds__(256) void k2(
    const float* __restrict__ partG, const float* __restrict__ p_att,
    const float* __restrict__ b_att, unsigned short* __restrict__ att)
{
  const int ns = blockIdx.x;
  for (int e = threadIdx.x; e < 1024; e += 256) {
    int u = e >> 5, v = e & 31;
    float a = 0.f;
    if (u < VV && v < VV) {
      float g = 0.f;
      #pragma unroll 4
      for (int tb = 0; tb < NTB; ++tb)
        g += partG[((size_t)tb * (NN * SS) + ns) * (VV * VV) + u * VV + v];
      a = tanhf(g * (1.0f / 4096.0f))
        + p_att[(size_t)ns * 100 + JP[u] * 10 + JP[v]]
        + b_att[(size_t)ns * 25  + JB[u] * 5  + JB[v]];
    }
    att[(size_t)ns * 1024 + e] = f2b(a);
  }
}

// ---------------------------------------------------------------------------
// k3: per (n, tb): VAL2 -> PV2 -> FF3, all LDS writes vectorized, 3 barriers.
//   VAL2: D[i'=0..127][cout] = xw . Wv^T   (A=xw rows, B=wbin rows, global)
//   PV2:  D[cm][u] per (s,dt=wid) = val . att^T (A=val rows LDS, B=att global)
//   FF3:  D[o][i] = Wff . yL^T  (A=wbff rows global, B=yL rows LDS)
// LDS: val[96][132] = 25344 B; yL[112][104] overlays val after barrier.
// ---------------------------------------------------------------------------
__global__ __launch_bounds__(256, 2) void k3(
    const float* __restrict__ x, const unsigned short* __restrict__ xw,
    const unsigned short* __restrict__ wbin,
    const unsigned short* __restrict__ wbff,
    const float* __restrict__ b_in, const float* __restrict__ scsh,
    const unsigned short* __restrict__ att, float* __restrict__ out)
{
  __shared__ __align__(16) unsigned short val[96 * VP];   // 25344 B
  unsigned short* yL = val;                               // [112][YP] overlay

  const int tid  = threadIdx.x;
  const int wid  = tid >> 6, lane = tid & 63;
  const int lrow = lane & 15;
  const int lk8  = (lane >> 4) << 3;
  const int ldr4 = (lane >> 4) << 2;
  const int tb = blockIdx.x & (NTB - 1);
  const int n  = blockIdx.x >> 5;
  const int t0 = tb * TB;

  const unsigned short* xwn = xw + (size_t)(n * TT + t0) * 32 * 96;

  // ---- VAL2 GEMM: wave handles m-frags {wid, wid+4} of 8
  f32x4 vacc[2][6];
  #pragma unroll
  for (int m = 0; m < 2; ++m)
    #pragma unroll
    for (int of = 0; of < 6; ++of) vacc[m][of] = fz();

  #pragma unroll
  for (int ks = 0; ks < 3; ++ks) {
    bf16x8 bw[6];
    #pragma unroll
    for (int of = 0; of < 6; ++of)
      bw[of] = ldbf8(&wbin[(192 + of * 16 + lrow) * 96 + ks * 32 + lk8]);
    #pragma unroll
    for (int m = 0; m < 2; ++m) {
      bf16x8 a = ldbf8(&xwn[(size_t)((wid + m * 4) * 16 + lrow) * 96 + ks * 32 + lk8]);
      #pragma unroll
      for (int of = 0; of < 6; ++of)
        vacc[m][of] = MFMA16(a, bw[of], vacc[m][of]);
    }
  }
  float bv[6];
  #pragma unroll
  for (int of = 0; of < 6; ++of) bv[of] = b_in[192 + of * 16 + lrow];

  // val[cout][i'] writes: 4 consecutive i' per lane -> ushort4; v-pads -> 0
  #pragma unroll
  for (int m = 0; m < 2; ++m) {
    int i0 = (wid + m * 4) * 16 + ldr4;     // i' base (4-aligned, 32-block safe)
    int v0 = i0 & 31;
    #pragma unroll
    for (int of = 0; of < 6; ++of) {
      int cout = of * 16 + lrow;
      ushort4 h;
      h.x = (v0 + 0 < VV) ? f2b(vacc[m][of][0] + bv[of]) : (unsigned short)0;
      h.y = (v0 + 1 < VV) ? f2b(vacc[m][of][1] + bv[of]) : (unsigned short)0;
      h.z = (v0 + 2 < VV) ? f2b(vacc[m][of][2] + bv[of]) : (unsigned short)0;
      h.w = (v0 + 3 < VV) ? f2b(vacc[m][of][3] + bv[of]) : (unsigned short)0;
      *(ushort4*)&val[cout * VP + i0] = h;
    }
  }
  __syncthreads();

  // ---- PV2: dt = wid; D[cm][u] per s; K = v (32)
  const unsigned short* attn = att + (size_t)n * SS * 1024;
  f32x4 pacc[3][2][2];
  #pragma unroll
  for (int s = 0; s < 3; ++s)
    #pragma unroll
    for (int mi = 0; mi < 2; ++mi)
      #pragma unroll
      for (int uf = 0; uf < 2; ++uf) pacc[s][mi][uf] = fz();

  #pragma unroll
  for (int s = 0; s < 3; ++s) {
    bf16x8 av[2], bu[2];
    #pragma unroll
    for (int mi = 0; mi < 2; ++mi)
      av[mi] = ldbf8(&val[(s * 32 + mi * 16 + lrow) * VP + wid * 32 + lk8]);
    #pragma unroll
    for (int uf = 0; uf < 2; ++uf)
      bu[uf] = ldbf8(&attn[s * 1024 + (uf * 16 + lrow) * 32 + lk8]);
    #pragma unroll
    for (int mi = 0; mi < 2; ++mi)
      #pragma unroll
      for (int uf = 0; uf < 2; ++uf)
        pacc[s][mi][uf] = MFMA16(av[mi], bu[uf], pacc[s][mi][uf]);
  }
  __syncthreads();   // val reads complete; yL may overlay

  // yL[dt*25+u][c]: 4 consecutive c per lane -> ushort4
  #pragma unroll
  for (int s = 0; s < 3; ++s)
    #pragma unroll
    for (int mi = 0; mi < 2; ++mi)
      #pragma unroll
      for (int uf = 0; uf < 2; ++uf) {
        int u = uf * 16 + lrow;
        if (u < VV) {
          int c0 = s * 32 + mi * 16 + ldr4;
          ushort4 h;
          h.x = f2b(pacc[s][mi][uf][0]);
          h.y = f2b(pacc[s][mi][uf][1]);
          h.z = f2b(pacc[s][mi][uf][2]);
          h.w = f2b(pacc[s][mi][uf][3]);
          *(ushort4*)&yL[(wid * VV + u) * YP + c0] = h;
        }
      }
  __syncthreads();

  // ---- FF3 + epilogue: wave handles col-frags {wid, wid+4} of 7
  #pragma unroll
  for (int rep = 0; rep < 2; ++rep) {
    int nf = wid + rep * 4;
    if (nf < 7) {
      f32x4 facc[6];
      #pragma unroll
      for (int of = 0; of < 6; ++of) facc[of] = fz();
      #pragma unroll
      for (int ks = 0; ks < 3; ++ks) {
        bf16x8 by = ldbf8(&yL[(nf * 16 + lrow) * YP + ks * 32 + lk8]);
        #pragma unroll
        for (int of = 0; of < 6; ++of) {
          bf16x8 aw = ldbf8(&wbff[(of * 16 + lrow) * 96 + ks * 32 + lk8]);
          facc[of] = MFMA16(aw, by, facc[of]);
        }
      }
      int i = nf * 16 + lrow;   // output col = i = dt*25+u
      if (i < ROWS) {
        size_t base = (size_t)n * CC * (TT * VV) + (size_t)t0 * VV + i;
        #pragma unroll
        for (int of = 0; of < 6; ++of) {
          int o0 = of * 16 + ldr4;
          float4 sc = *(const float4*)&scsh[o0];
          float4 sh = *(const float4*)&scsh[96 + o0];
          const float* scp = (const float*)&sc;
          const float* shp = (const float*)&sh;
          #pragma unroll
          for (int r = 0; r < 4; ++r) {
            size_t idx = base + (size_t)(o0 + r) * (TT * VV);
            float z = facc[of][r] * scp[r] + shp[r] + x[idx];
            out[idx] = (z >= 0.f) ? z : 0.1f * z;
          }
        }
      }
    }
  }
}

// ---------------------------------------------------------------------------
extern "C" void kernel_launch(void* const* d_in, const int* in_sizes, int n_in,
                              void* d_out, int out_size, void* d_ws, size_t ws_size,
                              hipStream_t stream)
{
  const float* x     = (const float*)d_in[0];
  const float* p_att = (const float*)d_in[1];
  const float* b_att = (const float*)d_in[2];
  const float* w_in  = (const float*)d_in[3];
  const float* b_in  = (const float*)d_in[4];
  const float* w_ff  = (const float*)d_in[5];
  const float* b_ff  = (const float*)d_in[6];
  const float* gam   = (const float*)d_in[7];
  const float* bet   = (const float*)d_in[8];
  const float* mea   = (const float*)d_in[9];
  const float* var   = (const float*)d_in[10];
  float* out = (float*)d_out;

  char* ws = (char*)d_ws;
  unsigned short* wbin = (unsigned short*)ws;              // 55296 B @0
  unsigned short* wbff = wbin + 288 * 96;                  // 18432 B
  unsigned short* attw = wbff + 96 * 96;                   // 393216 B
  float* scsh  = (float*)(ws + 466944);                    // 768 B
  float* partG = (float*)(ws + 467712);                    // 15,360,000 B
  unsigned short* xw = (unsigned short*)(ws + 15827712);   // 50,331,648 B

  k0<<<108, 256, 0, stream>>>(w_in, w_ff, b_ff, gam, bet, mea, var,
                              wbin, wbff, scsh);
  k1<<<NN * NTB, 256, 0, stream>>>(x, wbin, b_in, partG, xw);
  k2<<<NN * SS, 256, 0, stream>>>(partG, p_att, b_att, attw);
  k3<<<NN * NTB, 256, 0, stream>>>(x, xw, wbin, wbff, b_in, scsh, attw, out);
}

// Round 7
// 130.099 us; speedup vs baseline: 1.0222x; 1.0222x over previous
//
#include <hip/hip_runtime.h>
#include <cmath>

#define NN 64
#define CC 96
#define TT 128
#define VV 25
#define SS 3
#define TB 4
#define NTB (TT/TB)          /* 32 */
#define ROWS (TB*VV)         /* 100 */
#define XTROWS 112

#define XTP 104              /* k1 xT row pad (bf16 elems) */
#define XFP 104              /* xf [c][i] staging pitch */
#define QKP 200              /* k1 qk row pad */
#define X3P 104              /* k3 xT32 row pitch (rows = dt*32+v, 128 rows) */
#define VP  136              /* k3 val row pitch (128 i' cols + 8) */
#define YP  104              /* k3 yL row pitch */
#define WLP 104              /* k3 weight-LDS row pitch */

typedef __attribute__((ext_vector_type(8))) __bf16 bf16x8;
typedef __attribute__((ext_vector_type(4))) float f32x4;

#define MFMA16(a,b,c) __builtin_amdgcn_mfma_f32_16x16x32_bf16((a),(b),(c),0,0,0)

__constant__ int JP[25] = {0,0,1,1,2,2,2,3,4,4,4,5,6,6,7,7,8,8,9,9,0,3,3,5,5};
__constant__ int JB[25] = {4,4,4,4,0,0,0,0,1,1,1,1,2,2,2,2,3,3,3,3,4,0,0,1,1};

__device__ inline unsigned short f2b(float f) {
  unsigned int u = __float_as_uint(f);
  u += 0x7fffu + ((u >> 16) & 1u);
  return (unsigned short)(u >> 16);
}
__device__ inline bf16x8 ldbf8(const unsigned short* p) {
  union { uint4 u; bf16x8 b; } z;
  z.u = *(const uint4*)p;
  return z.b;
}
__device__ inline f32x4 fz() {
  f32x4 z; z[0] = 0.f; z[1] = 0.f; z[2] = 0.f; z[3] = 0.f; return z;
}

// ---------------------------------------------------------------------------
// k0: weights -> bf16 in ws; BN scale/shift precompute
// ---------------------------------------------------------------------------
__global__ __launch_bounds__(256) void k0(
    const float* __restrict__ w_in, const float* __restrict__ w_ff,
    const float* __restrict__ b_ff, const float* __restrict__ gam,
    const float* __restrict__ bet, const float* __restrict__ mea,
    const float* __restrict__ var,
    unsigned short* __restrict__ wbin, unsigned short* __restrict__ wbff,
    float* __restrict__ scsh)
{
  int i = blockIdx.x * 256 + threadIdx.x;
  if (i < 288 * 96) wbin[i] = f2b(w_in[i]);
  if (i < 96 * 96)  wbff[i] = f2b(w_ff[i]);
  if (i < 96) {
    float sc = gam[i] * rsqrtf(var[i] + 1e-5f);
    scsh[i]      = sc;
    scsh[96 + i] = (b_ff[i] - mea[i]) * sc + bet[i];
  }
}

// ---------------------------------------------------------------------------
// k1: per (n, tb): QK GEMM (MFMA) -> Gram partials   [round-5 proven version]
// ---------------------------------------------------------------------------
__device__ inline void stageA(const float* __restrict__ xb,
                              unsigned short* __restrict__ xf, int tid)
{
  for (int e = tid; e < CC * (ROWS / 4); e += 256) {
    int i4 = e % (ROWS / 4), c = e / (ROWS / 4);
    float4 v = *(const float4*)&xb[(size_t)c * (TT * VV) + i4 * 4];
    ushort4 h;
    h.x = f2b(v.x); h.y = f2b(v.y); h.z = f2b(v.z); h.w = f2b(v.w);
    *(ushort4*)&xf[c * XFP + i4 * 4] = h;
  }
}

__global__ __launch_bounds__(256, 2) void k1(
    const float* __restrict__ x, const unsigned short* __restrict__ wbin,
    const float* __restrict__ b_in, float* __restrict__ partG)
{
  __shared__ __align__(16) unsigned short xT[XTROWS * XTP];   // 23296 B
  __shared__ __align__(16) unsigned short qk[XTROWS * QKP];   // 44800 B; xf alias
  __shared__ float bL[192];
  unsigned short* xf = qk;

  const int tid  = threadIdx.x;
  const int wid  = tid >> 6, lane = tid & 63;
  const int lrow = lane & 15;
  const int lk8  = (lane >> 4) << 3;
  const int ldr4 = (lane >> 4) << 2;
  const int tb = blockIdx.x & (NTB - 1);
  const int n  = blockIdx.x >> 5;
  const int t0 = tb * TB;

  const float* xb = x + (size_t)n * CC * TT * VV + (size_t)t0 * VV;
  stageA(xb, xf, tid);
  if (tid < 192) bL[tid] = b_in[tid];
  __syncthreads();
  // LDS transpose xf[c][i] -> xT[i][c]
  for (int e = tid; e < ROWS * (CC / 4); e += 256) {
    int i = e % ROWS, c4 = e / ROWS;
    ushort4 h;
    h.x = xf[(c4 * 4 + 0) * XFP + i];
    h.y = xf[(c4 * 4 + 1) * XFP + i];
    h.z = xf[(c4 * 4 + 2) * XFP + i];
    h.w = xf[(c4 * 4 + 3) * XFP + i];
    *(ushort4*)&xT[i * XTP + c4 * 4] = h;
  }
  __syncthreads();

  // QK GEMM: D[o=0..191][col=0..111] ; wave handles mf = 3*wid..3*wid+2
  f32x4 acc[3][7];
  #pragma unroll
  for (int i = 0; i < 3; ++i)
    #pragma unroll
    for (int nf = 0; nf < 7; ++nf) acc[i][nf] = fz();

  #pragma unroll
  for (int ks = 0; ks < 3; ++ks) {
    bf16x8 a[3];
    #pragma unroll
    for (int i = 0; i < 3; ++i)
      a[i] = ldbf8(&wbin[((wid * 3 + i) * 16 + lrow) * 96 + ks * 32 + lk8]);
    #pragma unroll
    for (int nf = 0; nf < 7; ++nf) {
      bf16x8 b = ldbf8(&xT[(nf * 16 + lrow) * XTP + ks * 32 + lk8]);
      #pragma unroll
      for (int i = 0; i < 3; ++i)
        acc[i][nf] = MFMA16(a[i], b, acc[i][nf]);
    }
  }
  #pragma unroll
  for (int i = 0; i < 3; ++i) {
    int ob = (wid * 3 + i) * 16 + ldr4;
    float4 bb = *(const float4*)&bL[ob];
    #pragma unroll
    for (int nf = 0; nf < 7; ++nf) {
      int col = nf * 16 + lrow;
      ushort4 h;
      h.x = f2b(acc[i][nf][0] + bb.x);
      h.y = f2b(acc[i][nf][1] + bb.y);
      h.z = f2b(acc[i][nf][2] + bb.z);
      h.w = f2b(acc[i][nf][3] + bb.w);
      *(ushort4*)&qk[col * QKP + ob] = h;
    }
  }
  __syncthreads();

  // Gram: waves 0..2, s = wid
  if (wid < 3) {
    const int s = wid;
    f32x4 g[2][2];
    g[0][0] = fz(); g[0][1] = fz(); g[1][0] = fz(); g[1][1] = fz();
    #pragma unroll
    for (int dt = 0; dt < TB; ++dt) {
      int r0 = dt * VV;
      bf16x8 a0 = ldbf8(&qk[(r0 + lrow) * QKP + s * 32 + lk8]);
      bf16x8 a1 = ldbf8(&qk[(r0 + 16 + lrow) * QKP + s * 32 + lk8]);
      bf16x8 b0 = ldbf8(&qk[(r0 + lrow) * QKP + 96 + s * 32 + lk8]);
      bf16x8 b1 = ldbf8(&qk[(r0 + 16 + lrow) * QKP + 96 + s * 32 + lk8]);
      g[0][0] = MFMA16(a0, b0, g[0][0]);
      g[0][1] = MFMA16(a0, b1, g[0][1]);
      g[1][0] = MFMA16(a1, b0, g[1][0]);
      g[1][1] = MFMA16(a1, b1, g[1][1]);
    }
    float* pg = partG + ((size_t)tb * (NN * SS) + (n * SS + s)) * (VV * VV);
    #pragma unroll
    for (int mi = 0; mi < 2; ++mi)
      #pragma unroll
      for (int ni = 0; ni < 2; ++ni)
        #pragma unroll
        for (int r = 0; r < 4; ++r) {
          int u = mi * 16 + ldr4 + r, v = ni * 16 + lrow;
          if (u < VV && v < VV) pg[u * VV + v] = g[mi][ni][r];
        }
  }
}

// ---------------------------------------------------------------------------
// k2: reduce partials, tanh + positional gathers -> att bf16 [ns][32][32]
// ---------------------------------------------------------------------------
__global__ __launch_bounds__(256) void k2(
    const float* __restrict__ partG, const float* __restrict__ p_att,
    const float* __restrict__ b_att, unsigned short* __restrict__ att)
{
  const int ns = blockIdx.x;
  for (int e = threadIdx.x; e < 1024; e += 256) {
    int u = e >> 5, v = e & 31;
    float a = 0.f;
    if (u < VV && v < VV) {
      float g = 0.f;
      #pragma unroll 4
      for (int tb = 0; tb < NTB; ++tb)
        g += partG[((size_t)tb * (NN * SS) + ns) * (VV * VV) + u * VV + v];
      a = tanhf(g * (1.0f / 4096.0f))
        + p_att[(size_t)ns * 100 + JP[u] * 10 + JP[v]]
        + b_att[(size_t)ns * 25  + JB[u] * 5  + JB[v]];
    }
    att[(size_t)ns * 1024 + e] = f2b(a);
  }
}

// ---------------------------------------------------------------------------
// k3: per (n, tb): VAL -> PV -> FF, ALL weight MFMA fragments from LDS
// (staged coalesced). LDS ~73.9 KB -> 2 blocks/CU.
//   xT32 [128][104]: x^T, rows dt*32+v (pads zeroed); yL overlays after VAL.
//   val  [96][136] : [c][i'=dt*32+v]; xf staging aliases this region.
//   wL   [96][104] : wbin val-rows; wff overlays after VAL.
// ---------------------------------------------------------------------------
__global__ __launch_bounds__(256, 2) void k3(
    const float* __restrict__ x, const unsigned short* __restrict__ wbin,
    const unsigned short* __restrict__ wbff,
    const float* __restrict__ b_in, const float* __restrict__ scsh,
    const unsigned short* __restrict__ att, float* __restrict__ out)
{
  __shared__ __align__(16) unsigned short xT32[128 * X3P];  // 26624 B
  __shared__ __align__(16) unsigned short val[96 * VP];     // 26112 B
  __shared__ __align__(16) unsigned short wL[96 * WLP];     // 19968 B
  __shared__ float bvL[96];
  __shared__ float scshL[192];
  unsigned short* xf = val;   // staging alias (9984 ushorts <= 13056)
  unsigned short* yL = xT32;  // FF input overlay

  const int tid  = threadIdx.x;
  const int wid  = tid >> 6, lane = tid & 63;
  const int lrow = lane & 15;
  const int lk8  = (lane >> 4) << 3;
  const int ldr4 = (lane >> 4) << 2;
  const int tb = blockIdx.x & (NTB - 1);
  const int n  = blockIdx.x >> 5;
  const int t0 = tb * TB;

  const float* xb = x + (size_t)n * CC * TT * VV + (size_t)t0 * VV;

  // ---- phase 1: stage xf (coalesced), wL (wbin val rows, coalesced uint4),
  //      zero xT32 pad rows, bvL, scshL
  stageA(xb, xf, tid);
  for (int e = tid; e < 96 * 12; e += 256) {          // wbin[192..287][96]
    int r = e / 12, q = e % 12;
    *(uint4*)&wL[r * WLP + q * 8] =
        *(const uint4*)&wbin[(size_t)(192 + r) * 96 + q * 8];
  }
  for (int e = tid; e < 28 * 13; e += 256) {          // zero pad rows v>=25
    int pr = e / 13, q = e % 13;
    int row = (pr / 7) * 32 + 25 + (pr % 7);
    uint4 z; z.x = 0u; z.y = 0u; z.z = 0u; z.w = 0u;
    *(uint4*)&xT32[row * X3P + q * 8] = z;
  }
  if (tid < 96)  bvL[tid]   = b_in[192 + tid];
  if (tid < 192) scshL[tid] = scsh[tid];
  __syncthreads();

  // ---- phase 2: LDS transpose xf[c][i] -> xT32[dt*32+v][c]
  for (int e = tid; e < ROWS * (CC / 4); e += 256) {
    int i = e % ROWS, c4 = e / ROWS;
    int row = (i / VV) * 32 + (i % VV);
    ushort4 h;
    h.x = xf[(c4 * 4 + 0) * XFP + i];
    h.y = xf[(c4 * 4 + 1) * XFP + i];
    h.z = xf[(c4 * 4 + 2) * XFP + i];
    h.w = xf[(c4 * 4 + 3) * XFP + i];
    *(ushort4*)&xT32[row * X3P + c4 * 4] = h;
  }
  __syncthreads();

  // ---- phase 3: VAL GEMM  D[i'][cout]; A = xT32 rows i', B = wL rows c.
  // wave handles i'-frags {wid, wid+4}
  f32x4 vacc[2][6];
  #pragma unroll
  for (int m = 0; m < 2; ++m)
    #pragma unroll
    for (int of = 0; of < 6; ++of) vacc[m][of] = fz();

  #pragma unroll
  for (int ks = 0; ks < 3; ++ks) {
    bf16x8 bw[6];
    #pragma unroll
    for (int of = 0; of < 6; ++of)
      bw[of] = ldbf8(&wL[(of * 16 + lrow) * WLP + ks * 32 + lk8]);
    #pragma unroll
    for (int m = 0; m < 2; ++m) {
      bf16x8 a = ldbf8(&xT32[((wid + m * 4) * 16 + lrow) * X3P + ks * 32 + lk8]);
      #pragma unroll
      for (int of = 0; of < 6; ++of)
        vacc[m][of] = MFMA16(a, bw[of], vacc[m][of]);
    }
  }
  float bv[6];
  #pragma unroll
  for (int of = 0; of < 6; ++of) bv[of] = bvL[of * 16 + lrow];

  // val[cout][i'] ushort4 writes; v-pads -> 0
  #pragma unroll
  for (int m = 0; m < 2; ++m) {
    int i0 = (wid + m * 4) * 16 + ldr4;
    int v0 = i0 & 31;
    #pragma unroll
    for (int of = 0; of < 6; ++of) {
      int cout = of * 16 + lrow;
      ushort4 h;
      h.x = (v0 + 0 < VV) ? f2b(vacc[m][of][0] + bv[of]) : (unsigned short)0;
      h.y = (v0 + 1 < VV) ? f2b(vacc[m][of][1] + bv[of]) : (unsigned short)0;
      h.z = (v0 + 2 < VV) ? f2b(vacc[m][of][2] + bv[of]) : (unsigned short)0;
      h.w = (v0 + 3 < VV) ? f2b(vacc[m][of][3] + bv[of]) : (unsigned short)0;
      *(ushort4*)&val[cout * VP + i0] = h;
    }
  }
  __syncthreads();

  // ---- phase 4: load wff into wL (overlay) + PV + yL writes
  for (int e = tid; e < 96 * 12; e += 256) {
    int r = e / 12, q = e % 12;
    *(uint4*)&wL[r * WLP + q * 8] =
        *(const uint4*)&wbff[(size_t)r * 96 + q * 8];
  }

  // PV: dt = wid; D[c][u] per s; A = val rows c (K window dt*32), B = att rows u
  const unsigned short* attn = att + (size_t)n * SS * 1024;
  f32x4 pacc[3][2][2];
  #pragma unroll
  for (int s = 0; s < 3; ++s)
    #pragma unroll
    for (int mi = 0; mi < 2; ++mi)
      #pragma unroll
      for (int uf = 0; uf < 2; ++uf) pacc[s][mi][uf] = fz();

  #pragma unroll
  for (int s = 0; s < 3; ++s) {
    bf16x8 av[2], bu[2];
    #pragma unroll
    for (int mi = 0; mi < 2; ++mi)
      av[mi] = ldbf8(&val[(s * 32 + mi * 16 + lrow) * VP + wid * 32 + lk8]);
    #pragma unroll
    for (int uf = 0; uf < 2; ++uf)
      bu[uf] = ldbf8(&attn[s * 1024 + (uf * 16 + lrow) * 32 + lk8]);
    #pragma unroll
    for (int mi = 0; mi < 2; ++mi)
      #pragma unroll
      for (int uf = 0; uf < 2; ++uf)
        pacc[s][mi][uf] = MFMA16(av[mi], bu[uf], pacc[s][mi][uf]);
  }

  // yL[dt*25+u][c] ushort4 writes (overlays xT32; xT32 dead after VAL)
  #pragma unroll
  for (int s = 0; s < 3; ++s)
    #pragma unroll
    for (int mi = 0; mi < 2; ++mi)
      #pragma unroll
      for (int uf = 0; uf < 2; ++uf) {
        int u = uf * 16 + lrow;
        if (u < VV) {
          int c0 = s * 32 + mi * 16 + ldr4;
          ushort4 h;
          h.x = f2b(pacc[s][mi][uf][0]);
          h.y = f2b(pacc[s][mi][uf][1]);
          h.z = f2b(pacc[s][mi][uf][2]);
          h.w = f2b(pacc[s][mi][uf][3]);
          *(ushort4*)&yL[(wid * VV + u) * YP + c0] = h;
        }
      }
  __syncthreads();

  // ---- phase 5: FF GEMM D[o][i]; A = wL(wff) rows o, B = yL rows i + epilogue
  #pragma unroll
  for (int rep = 0; rep < 2; ++rep) {
    int nf = wid + rep * 4;
    if (nf < 7) {
      f32x4 facc[6];
      #pragma unroll
      for (int of = 0; of < 6; ++of) facc[of] = fz();
      #pragma unroll
      for (int ks = 0; ks < 3; ++ks) {
        bf16x8 by = ldbf8(&yL[(nf * 16 + lrow) * YP + ks * 32 + lk8]);
        #pragma unroll
        for (int of = 0; of < 6; ++of) {
          bf16x8 aw = ldbf8(&wL[(of * 16 + lrow) * WLP + ks * 32 + lk8]);
          facc[of] = MFMA16(aw, by, facc[of]);
        }
      }
      int i = nf * 16 + lrow;
      if (i < ROWS) {
        size_t base = (size_t)n * CC * (TT * VV) + (size_t)t0 * VV + i;
        #pragma unroll
        for (int of = 0; of < 6; ++of) {
          int o0 = of * 16 + ldr4;
          float4 sc = *(const float4*)&scshL[o0];
          float4 sh = *(const float4*)&scshL[96 + o0];
          const float* scp = (const float*)&sc;
          const float* shp = (const float*)&sh;
          #pragma unroll
          for (int r = 0; r < 4; ++r) {
            size_t idx = base + (size_t)(o0 + r) * (TT * VV);
            float z = facc[of][r] * scp[r] + shp[r] + x[idx];
            out[idx] = (z >= 0.f) ? z : 0.1f * z;
          }
        }
      }
    }
  }
}

// ---------------------------------------------------------------------------
extern "C" void kernel_launch(void* const* d_in, const int* in_sizes, int n_in,
                              void* d_out, int out_size, void* d_ws, size_t ws_size,
                              hipStream_t stream)
{
  const float* x     = (const float*)d_in[0];
  const float* p_att = (const float*)d_in[1];
  const float* b_att = (const float*)d_in[2];
  const float* w_in  = (const float*)d_in[3];
  const float* b_in  = (const float*)d_in[4];
  const float* w_ff  = (const float*)d_in[5];
  const float* b_ff  = (const float*)d_in[6];
  const float* gam   = (const float*)d_in[7];
  const float* bet   = (const float*)d_in[8];
  const float* mea   = (const float*)d_in[9];
  const float* var   = (const float*)d_in[10];
  float* out = (float*)d_out;

  char* ws = (char*)d_ws;
  unsigned short* wbin = (unsigned short*)ws;              // 55296 B @0
  unsigned short* wbff = wbin + 288 * 96;                  // 18432 B
  unsigned short* attw = wbff + 96 * 96;                   // 393216 B
  float* scsh  = (float*)(ws + 466944);                    // 768 B
  float* partG = (float*)(ws + 467712);                    // 15,360,000 B

  k0<<<108, 256, 0, stream>>>(w_in, w_ff, b_ff, gam, bet, mea, var,
                              wbin, wbff, scsh);
  k1<<<NN * NTB, 256, 0, stream>>>(x, wbin, b_in, partG);
  k2<<<NN * SS, 256, 0, stream>>>(partG, p_att, b_att, attw);
  k3<<<NN * NTB, 256, 0, stream>>>(x, wbin, wbff, b_in, scsh, attw, out);
}